// Round 1
// baseline (207.641 us; speedup 1.0000x reference)
//
#include <hip/hip_runtime.h>

#define NB 8
#define NV 100000
#define NE 300000
#define CLIPV 0.9999999f  // 1 - 1e-7 rounded to f32

struct F3 { float x, y, z; };

__device__ __forceinline__ F3 loadv(const float* __restrict__ v, int i) {
    const float* p = v + 3LL * i;
    F3 r; r.x = p[0]; r.y = p[1]; r.z = p[2]; return r;
}
__device__ __forceinline__ F3 sub3(F3 a, F3 b) {
    F3 r; r.x = a.x - b.x; r.y = a.y - b.y; r.z = a.z - b.z; return r;
}
__device__ __forceinline__ F3 cross3(F3 a, F3 b) {
    F3 r;
    r.x = a.y * b.z - a.z * b.y;
    r.y = a.z * b.x - a.x * b.z;
    r.z = a.x * b.y - a.y * b.x;
    return r;
}

// angle = pi - acos(clip(dot(na_hat, nb_hat)))
__device__ __forceinline__ float edge_angle(F3 p0, F3 p1, F3 p2, F3 p3) {
    // face_normal(0): i=0 -> base p0, ea = p2-p0, eb = p1-p0
    F3 na = cross3(sub3(p2, p0), sub3(p1, p0));
    // face_normal(3): i=1 -> base p1, ea = p3-p1, eb = p0-p1
    F3 nb = cross3(sub3(p3, p1), sub3(p0, p1));
    float la = fmaxf(sqrtf(na.x * na.x + na.y * na.y + na.z * na.z), 1e-12f);
    float lb = fmaxf(sqrtf(nb.x * nb.x + nb.y * nb.y + nb.z * nb.z), 1e-12f);
    float ra = 1.0f / la;
    float rb = 1.0f / lb;
    // zero normal (degenerate edge): na==0 exactly -> dot=0 -> angle=pi/2, matches ref
    float d = (na.x * nb.x + na.y * nb.y + na.z * nb.z) * ra * rb;
    d = fminf(fmaxf(d, -CLIPV), CLIPV);
    return 3.14159265358979323846f - acosf(d);
}

__global__ void mdal_zero_ws_kernel(double* __restrict__ ws) {
    if (threadIdx.x == 0 && blockIdx.x == 0) ws[0] = 0.0;
}

__global__ __launch_bounds__(256) void mdal_main_kernel(
    const float* __restrict__ vert1,
    const float* __restrict__ vert2,
    const int* __restrict__ edge_points,
    double* __restrict__ ws)
{
    const int e = blockIdx.x * 256 + threadIdx.x;
    const int b = blockIdx.y;

    double acc = 0.0;
    if (e < NE) {
        const long long gid = (long long)b * NE + e;
        const int4 idx = reinterpret_cast<const int4*>(edge_points)[gid];
        const float* __restrict__ v1 = vert1 + (long long)b * NV * 3;
        const float* __restrict__ v2 = vert2 + (long long)b * NV * 3;

        float a1 = edge_angle(loadv(v1, idx.x), loadv(v1, idx.y),
                              loadv(v1, idx.z), loadv(v1, idx.w));
        float a2 = edge_angle(loadv(v2, idx.x), loadv(v2, idx.y),
                              loadv(v2, idx.z), loadv(v2, idx.w));
        float d = a1 - a2;
        acc = (double)d * (double)d;
    }

    // wave (64-lane) reduction
    for (int off = 32; off > 0; off >>= 1)
        acc += __shfl_down(acc, off);

    __shared__ double sdata[4];
    const int lane = threadIdx.x & 63;
    const int wave = threadIdx.x >> 6;
    if (lane == 0) sdata[wave] = acc;
    __syncthreads();
    if (threadIdx.x == 0) {
        double s = sdata[0] + sdata[1] + sdata[2] + sdata[3];
        atomicAdd(ws, s);
    }
}

__global__ void mdal_finalize_kernel(const double* __restrict__ ws,
                                     float* __restrict__ out) {
    if (threadIdx.x == 0 && blockIdx.x == 0)
        out[0] = (float)(ws[0] / (double)((long long)NB * NE));
}

extern "C" void kernel_launch(void* const* d_in, const int* in_sizes, int n_in,
                              void* d_out, int out_size, void* d_ws, size_t ws_size,
                              hipStream_t stream) {
    const float* vert1 = (const float*)d_in[0];
    const float* vert2 = (const float*)d_in[1];
    const int* edge_points = (const int*)d_in[2];
    float* out = (float*)d_out;
    double* ws = (double*)d_ws;

    mdal_zero_ws_kernel<<<1, 64, 0, stream>>>(ws);

    dim3 grid((NE + 255) / 256, NB);
    mdal_main_kernel<<<grid, 256, 0, stream>>>(vert1, vert2, edge_points, ws);

    mdal_finalize_kernel<<<1, 64, 0, stream>>>(ws, out);
}

// Round 4
// 180.811 us; speedup vs baseline: 1.1484x; 1.1484x over previous
//
#include <hip/hip_runtime.h>

#define NB 8
#define NV 100000
#define NE 300000
#define CLIPV 0.9999999f  // 1 - 1e-7 rounded to f32

#define TPB 256
#define EPT 2                         // edges per thread
#define EPB (TPB * EPT)               // 512 edges per block
#define CHUNKS ((NE + EPB - 1) / EPB) // 586 chunks per batch

typedef int v4i __attribute__((ext_vector_type(4)));

struct F3 { float x, y, z; };

__device__ __forceinline__ F3 loadv(const float* __restrict__ v, int i) {
    const float* p = v + 3LL * i;
    F3 r; r.x = p[0]; r.y = p[1]; r.z = p[2]; return r;
}
__device__ __forceinline__ F3 sub3(F3 a, F3 b) {
    F3 r; r.x = a.x - b.x; r.y = a.y - b.y; r.z = a.z - b.z; return r;
}
__device__ __forceinline__ F3 cross3(F3 a, F3 b) {
    F3 r;
    r.x = a.y * b.z - a.z * b.y;
    r.y = a.z * b.x - a.x * b.z;
    r.z = a.x * b.y - a.y * b.x;
    return r;
}

// angle = pi - acos(clip(dot(na_hat, nb_hat)))
__device__ __forceinline__ float edge_angle(F3 p0, F3 p1, F3 p2, F3 p3) {
    // face_normal(0): i=0 -> base p0, ea = p2-p0, eb = p1-p0
    F3 na = cross3(sub3(p2, p0), sub3(p1, p0));
    // face_normal(3): i=1 -> base p1, ea = p3-p1, eb = p0-p1
    F3 nb = cross3(sub3(p3, p1), sub3(p0, p1));
    float la = fmaxf(sqrtf(na.x * na.x + na.y * na.y + na.z * na.z), 1e-12f);
    float lb = fmaxf(sqrtf(nb.x * nb.x + nb.y * nb.y + nb.z * nb.z), 1e-12f);
    // zero normal (degenerate edge): na==0 exactly -> dot=0 -> angle=pi/2, matches ref
    float d = (na.x * nb.x + na.y * nb.y + na.z * nb.z) * (1.0f / la) * (1.0f / lb);
    d = fminf(fmaxf(d, -CLIPV), CLIPV);
    return 3.14159265358979323846f - acosf(d);
}

__global__ void mdal_zero_ws_kernel(double* __restrict__ ws) {
    if (threadIdx.x == 0 && blockIdx.x == 0) ws[0] = 0.0;
}

__global__ __launch_bounds__(TPB, 4) void mdal_main_kernel(
    const float* __restrict__ vert1,
    const float* __restrict__ vert2,
    const int* __restrict__ edge_points,
    double* __restrict__ ws)
{
    const int bid = blockIdx.x;
    const int b = bid & (NB - 1);   // XCD swizzle: consecutive bids -> different XCDs,
    const int chunk = bid >> 3;     // so XCD k serves only batch k (L2-resident verts)

    const v4i* __restrict__ ep =
        reinterpret_cast<const v4i*>(edge_points) + (long long)b * NE;
    const float* __restrict__ v1 = vert1 + (long long)b * NV * 3;
    const float* __restrict__ v2 = vert2 + (long long)b * NV * 3;

    const int e0 = chunk * EPB + threadIdx.x;

    // --- stage 1: issue all index loads (nontemporal: pure streaming, keep L2 for verts)
    v4i idx[EPT];
    bool ok[EPT];
    #pragma unroll
    for (int k = 0; k < EPT; ++k) {
        const int e = e0 + k * TPB;
        ok[k] = (e < NE);
        if (ok[k]) {
            idx[k] = __builtin_nontemporal_load(&ep[e]);
        } else {
            idx[k] = (v4i){0, 0, 0, 0};
        }
    }

    // --- stage 2: issue ALL vertex gathers before any compute (ILP / latency hiding)
    F3 A[EPT][4], Bv[EPT][4];
    #pragma unroll
    for (int k = 0; k < EPT; ++k) {
        A[k][0] = loadv(v1, idx[k].x);
        A[k][1] = loadv(v1, idx[k].y);
        A[k][2] = loadv(v1, idx[k].z);
        A[k][3] = loadv(v1, idx[k].w);
        Bv[k][0] = loadv(v2, idx[k].x);
        Bv[k][1] = loadv(v2, idx[k].y);
        Bv[k][2] = loadv(v2, idx[k].z);
        Bv[k][3] = loadv(v2, idx[k].w);
    }

    // --- stage 3: compute
    double acc = 0.0;
    #pragma unroll
    for (int k = 0; k < EPT; ++k) {
        float a1 = edge_angle(A[k][0], A[k][1], A[k][2], A[k][3]);
        float a2 = edge_angle(Bv[k][0], Bv[k][1], Bv[k][2], Bv[k][3]);
        float d = a1 - a2;
        if (ok[k]) acc += (double)d * (double)d;
    }

    // --- wave (64-lane) reduction, then block, then one atomic
    for (int off = 32; off > 0; off >>= 1)
        acc += __shfl_down(acc, off);

    __shared__ double sdata[TPB / 64];
    const int lane = threadIdx.x & 63;
    const int wave = threadIdx.x >> 6;
    if (lane == 0) sdata[wave] = acc;
    __syncthreads();
    if (threadIdx.x == 0) {
        double s = 0.0;
        #pragma unroll
        for (int w = 0; w < TPB / 64; ++w) s += sdata[w];
        atomicAdd(ws, s);
    }
}

__global__ void mdal_finalize_kernel(const double* __restrict__ ws,
                                     float* __restrict__ out) {
    if (threadIdx.x == 0 && blockIdx.x == 0)
        out[0] = (float)(ws[0] / (double)((long long)NB * NE));
}

extern "C" void kernel_launch(void* const* d_in, const int* in_sizes, int n_in,
                              void* d_out, int out_size, void* d_ws, size_t ws_size,
                              hipStream_t stream) {
    const float* vert1 = (const float*)d_in[0];
    const float* vert2 = (const float*)d_in[1];
    const int* edge_points = (const int*)d_in[2];
    float* out = (float*)d_out;
    double* ws = (double*)d_ws;

    mdal_zero_ws_kernel<<<1, 64, 0, stream>>>(ws);

    mdal_main_kernel<<<CHUNKS * NB, TPB, 0, stream>>>(vert1, vert2, edge_points, ws);

    mdal_finalize_kernel<<<1, 64, 0, stream>>>(ws, out);
}

// Round 6
// 163.780 us; speedup vs baseline: 1.2678x; 1.1040x over previous
//
#include <hip/hip_runtime.h>

#define NB 8
#define NV 100000
#define NE 300000
#define CLIPV 0.9999999f  // 1 - 1e-7 rounded to f32

#define TPB 256
#define EPT 2                         // edges per thread
#define EPB (TPB * EPT)               // 512 edges per block
#define CHUNKS ((NE + EPB - 1) / EPB) // 586 chunks per batch
#define VCHUNKS ((NV + TPB - 1) / TPB)

#define PK_OFF 256                    // byte offset of packed verts in ws
#define PK_BYTES ((size_t)NB * NV * 8 * sizeof(float))

typedef int v4i __attribute__((ext_vector_type(4)));
typedef float v4f __attribute__((ext_vector_type(4)));

struct F3 { float x, y, z; };

__device__ __forceinline__ F3 loadv(const float* __restrict__ v, int i) {
    const float* p = v + 3LL * i;
    F3 r; r.x = p[0]; r.y = p[1]; r.z = p[2]; return r;
}
__device__ __forceinline__ F3 sub3(F3 a, F3 b) {
    F3 r; r.x = a.x - b.x; r.y = a.y - b.y; r.z = a.z - b.z; return r;
}
__device__ __forceinline__ F3 cross3(F3 a, F3 b) {
    F3 r;
    r.x = a.y * b.z - a.z * b.y;
    r.y = a.z * b.x - a.x * b.z;
    r.z = a.x * b.y - a.y * b.x;
    return r;
}

// angle = pi - acos(clip(dot(na_hat, nb_hat)))
__device__ __forceinline__ float edge_angle(F3 p0, F3 p1, F3 p2, F3 p3) {
    // face_normal(0): i=0 -> base p0, ea = p2-p0, eb = p1-p0
    F3 na = cross3(sub3(p2, p0), sub3(p1, p0));
    // face_normal(3): i=1 -> base p1, ea = p3-p1, eb = p0-p1
    F3 nb = cross3(sub3(p3, p1), sub3(p0, p1));
    float la = fmaxf(sqrtf(na.x * na.x + na.y * na.y + na.z * na.z), 1e-12f);
    float lb = fmaxf(sqrtf(nb.x * nb.x + nb.y * nb.y + nb.z * nb.z), 1e-12f);
    // zero normal (degenerate edge): na==0 exactly -> dot=0 -> angle=pi/2, matches ref
    float d = (na.x * nb.x + na.y * nb.y + na.z * nb.z) * (1.0f / la) * (1.0f / lb);
    d = fminf(fmaxf(d, -CLIPV), CLIPV);
    return 3.14159265358979323846f - acosf(d);
}

__global__ void mdal_zero_ws_kernel(double* __restrict__ ws) {
    if (threadIdx.x == 0 && blockIdx.x == 0) ws[0] = 0.0;
}

// Interleave vert1/vert2 into 32B records [x1,y1,z1,x2,y2,z2,0,0] in ws.
// XCD-pinned the same way as the main kernel so records stage into the
// consuming XCD's L2.
__global__ __launch_bounds__(TPB) void mdal_repack_kernel(
    const float* __restrict__ vert1,
    const float* __restrict__ vert2,
    float* __restrict__ pk)
{
    const int bid = blockIdx.x;
    const int b = bid & (NB - 1);
    const int chunk = bid >> 3;
    const int v = chunk * TPB + threadIdx.x;
    if (v >= NV) return;
    const long long src = ((long long)b * NV + v) * 3;
    const long long dst = ((long long)b * NV + v) * 8;
    float x1 = vert1[src], y1 = vert1[src + 1], z1 = vert1[src + 2];
    float x2 = vert2[src], y2 = vert2[src + 1], z2 = vert2[src + 2];
    v4f lo = {x1, y1, z1, x2};
    v4f hi = {y2, z2, 0.0f, 0.0f};
    *reinterpret_cast<v4f*>(pk + dst) = lo;
    *reinterpret_cast<v4f*>(pk + dst + 4) = hi;
}

__global__ __launch_bounds__(TPB, 4) void mdal_main_pk_kernel(
    const float* __restrict__ pk,
    const int* __restrict__ edge_points,
    double* __restrict__ ws)
{
    const int bid = blockIdx.x;
    const int b = bid & (NB - 1);   // XCD swizzle: XCD k serves only batch k
    const int chunk = bid >> 3;

    const v4i* __restrict__ ep =
        reinterpret_cast<const v4i*>(edge_points) + (long long)b * NE;
    const float* __restrict__ pkb = pk + (long long)b * NV * 8;

    const int e0 = chunk * EPB + threadIdx.x;

    // --- stage 1: index loads (nontemporal: pure stream, keep L2 for verts)
    v4i idx[EPT];
    bool ok[EPT];
    #pragma unroll
    for (int k = 0; k < EPT; ++k) {
        const int e = e0 + k * TPB;
        ok[k] = (e < NE);
        if (ok[k]) {
            idx[k] = __builtin_nontemporal_load(&ep[e]);
        } else {
            idx[k] = (v4i){0, 0, 0, 0};
        }
    }

    // --- stage 2: ALL packed-vertex gathers (one 64B line per edge-vertex)
    v4f L[EPT][4], H[EPT][4];
    #pragma unroll
    for (int k = 0; k < EPT; ++k) {
        #pragma unroll
        for (int j = 0; j < 4; ++j) {
            const int vid = (j == 0) ? idx[k].x : (j == 1) ? idx[k].y
                          : (j == 2) ? idx[k].z : idx[k].w;
            const v4f* p = reinterpret_cast<const v4f*>(pkb + (long long)vid * 8);
            L[k][j] = p[0];
            H[k][j] = p[1];
        }
    }

    // keep all gathers issued before any compute is scheduled
    __builtin_amdgcn_sched_barrier(0);

    // --- stage 3: compute
    double acc = 0.0;
    #pragma unroll
    for (int k = 0; k < EPT; ++k) {
        F3 A[4], Bv[4];
        #pragma unroll
        for (int j = 0; j < 4; ++j) {
            A[j].x = L[k][j].x; A[j].y = L[k][j].y; A[j].z = L[k][j].z;
            Bv[j].x = L[k][j].w; Bv[j].y = H[k][j].x; Bv[j].z = H[k][j].y;
        }
        float a1 = edge_angle(A[0], A[1], A[2], A[3]);
        float a2 = edge_angle(Bv[0], Bv[1], Bv[2], Bv[3]);
        float d = a1 - a2;
        if (ok[k]) acc += (double)d * (double)d;
    }

    // --- wave (64-lane) reduction, then block, then one atomic
    for (int off = 32; off > 0; off >>= 1)
        acc += __shfl_down(acc, off);

    __shared__ double sdata[TPB / 64];
    const int lane = threadIdx.x & 63;
    const int wave = threadIdx.x >> 6;
    if (lane == 0) sdata[wave] = acc;
    __syncthreads();
    if (threadIdx.x == 0) {
        double s = 0.0;
        #pragma unroll
        for (int w = 0; w < TPB / 64; ++w) s += sdata[w];
        atomicAdd(ws, s);
    }
}

// --- fallback path (no workspace repack), proven at 99us ---
__global__ __launch_bounds__(TPB, 4) void mdal_main_kernel(
    const float* __restrict__ vert1,
    const float* __restrict__ vert2,
    const int* __restrict__ edge_points,
    double* __restrict__ ws)
{
    const int bid = blockIdx.x;
    const int b = bid & (NB - 1);
    const int chunk = bid >> 3;

    const v4i* __restrict__ ep =
        reinterpret_cast<const v4i*>(edge_points) + (long long)b * NE;
    const float* __restrict__ v1 = vert1 + (long long)b * NV * 3;
    const float* __restrict__ v2 = vert2 + (long long)b * NV * 3;

    const int e0 = chunk * EPB + threadIdx.x;

    v4i idx[EPT];
    bool ok[EPT];
    #pragma unroll
    for (int k = 0; k < EPT; ++k) {
        const int e = e0 + k * TPB;
        ok[k] = (e < NE);
        if (ok[k]) {
            idx[k] = __builtin_nontemporal_load(&ep[e]);
        } else {
            idx[k] = (v4i){0, 0, 0, 0};
        }
    }

    F3 A[EPT][4], Bv[EPT][4];
    #pragma unroll
    for (int k = 0; k < EPT; ++k) {
        A[k][0] = loadv(v1, idx[k].x);
        A[k][1] = loadv(v1, idx[k].y);
        A[k][2] = loadv(v1, idx[k].z);
        A[k][3] = loadv(v1, idx[k].w);
        Bv[k][0] = loadv(v2, idx[k].x);
        Bv[k][1] = loadv(v2, idx[k].y);
        Bv[k][2] = loadv(v2, idx[k].z);
        Bv[k][3] = loadv(v2, idx[k].w);
    }

    double acc = 0.0;
    #pragma unroll
    for (int k = 0; k < EPT; ++k) {
        float a1 = edge_angle(A[k][0], A[k][1], A[k][2], A[k][3]);
        float a2 = edge_angle(Bv[k][0], Bv[k][1], Bv[k][2], Bv[k][3]);
        float d = a1 - a2;
        if (ok[k]) acc += (double)d * (double)d;
    }

    for (int off = 32; off > 0; off >>= 1)
        acc += __shfl_down(acc, off);

    __shared__ double sdata[TPB / 64];
    const int lane = threadIdx.x & 63;
    const int wave = threadIdx.x >> 6;
    if (lane == 0) sdata[wave] = acc;
    __syncthreads();
    if (threadIdx.x == 0) {
        double s = 0.0;
        #pragma unroll
        for (int w = 0; w < TPB / 64; ++w) s += sdata[w];
        atomicAdd(ws, s);
    }
}

__global__ void mdal_finalize_kernel(const double* __restrict__ ws,
                                     float* __restrict__ out) {
    if (threadIdx.x == 0 && blockIdx.x == 0)
        out[0] = (float)(ws[0] / (double)((long long)NB * NE));
}

extern "C" void kernel_launch(void* const* d_in, const int* in_sizes, int n_in,
                              void* d_out, int out_size, void* d_ws, size_t ws_size,
                              hipStream_t stream) {
    const float* vert1 = (const float*)d_in[0];
    const float* vert2 = (const float*)d_in[1];
    const int* edge_points = (const int*)d_in[2];
    float* out = (float*)d_out;
    double* ws = (double*)d_ws;

    mdal_zero_ws_kernel<<<1, 64, 0, stream>>>(ws);

    if (ws_size >= PK_OFF + PK_BYTES) {
        float* pk = (float*)((char*)d_ws + PK_OFF);
        mdal_repack_kernel<<<VCHUNKS * NB, TPB, 0, stream>>>(vert1, vert2, pk);
        mdal_main_pk_kernel<<<CHUNKS * NB, TPB, 0, stream>>>(pk, edge_points, ws);
    } else {
        mdal_main_kernel<<<CHUNKS * NB, TPB, 0, stream>>>(vert1, vert2, edge_points, ws);
    }

    mdal_finalize_kernel<<<1, 64, 0, stream>>>(ws, out);
}